// Round 2
// 406.212 us; speedup vs baseline: 1.2551x; 1.2551x over previous
//
#include <hip/hip_runtime.h>
#include <hip/hip_bf16.h>
#include <math.h>

typedef __bf16 bf16x8 __attribute__((ext_vector_type(8)));
typedef __bf16 bf16x4 __attribute__((ext_vector_type(4)));
typedef float  f32x4  __attribute__((ext_vector_type(4)));

constexpr int D   = 128;
constexpr int LQ  = 2048;
constexpr int SK  = 2048;
constexpr int BM  = 256;  // queries per block (8 waves x 32 rows)
constexpr int BN  = 64;   // keys per iteration
constexpr int NKV = 16;   // B*H distinct KV heads

__device__ __forceinline__ void load_lds16(const void* g, void* l) {
  __builtin_amdgcn_global_load_lds((const __attribute__((address_space(1))) unsigned*)g,
                                   (__attribute__((address_space(3))) unsigned*)l, 16, 0, 0);
}

// ---- prologue A: K fp32 -> Khi/Klo bf16 (elementwise, coalesced)
__global__ __launch_bounds__(256) void conv_k(const float* __restrict__ k,
                                              __bf16* __restrict__ khi,
                                              __bf16* __restrict__ klo) {
  const size_t i = ((size_t)blockIdx.x * 256 + threadIdx.x) * 4;
  f32x4 a = *(const f32x4*)(k + i);
  bf16x4 hi, lo;
#pragma unroll
  for (int j = 0; j < 4; ++j) {
    hi[j] = (__bf16)a[j];
    lo[j] = (__bf16)(a[j] - (float)hi[j]);
  }
  *(bf16x4*)(khi + i) = hi;
  *(bf16x4*)(klo + i) = lo;
}

// ---- prologue B: V fp32 [bh][s][d] -> Vt bf16 [bh][d][s]
__global__ __launch_bounds__(256) void transpose_v(const float* __restrict__ v,
                                                   __bf16* __restrict__ vt) {
  const int b    = blockIdx.x;        // 1024 = 16 bh x 64
  const int bh   = b >> 6;
  const int blk2 = b & 63;
  const int t    = threadIdx.x;
  const int s0   = (blk2 * 2 + (t >> 7)) * 16;
  const int d    = t & 127;
  const float* src = v + ((size_t)bh * SK + s0) * D + d;
  bf16x8 o0, o1;
#pragma unroll
  for (int j = 0; j < 8; ++j) o0[j] = (__bf16)src[j * D];
#pragma unroll
  for (int j = 0; j < 8; ++j) o1[j] = (__bf16)src[(8 + j) * D];
  __bf16* dst = vt + ((size_t)bh * D + d) * SK + s0;
  *(bf16x8*)dst = o0;
  *(bf16x8*)(dst + 8) = o1;
}

// ---- main: flash GQA, 8 waves x 32 q-rows, double-buffered LDS with
// prefetch-ahead (stage tile t+1 before computing tile t; one barrier/iter).
// Swapped QK^T: sf = mfma(K,Q) => lane holds P[16 keys] of ONE query row
// (query = 32*wave+16u+i16) -> lane-local softmax (2 shfl_xor over quads).
// PV swapped with k-slot permutation kappa(t,quad,j)=32t+16(j>>2)+4quad+(j&3)
// applied to BOTH P-frag (lane-local bf16 pack, no exchange) and V-frag
// (2x ds_read_b64 from the XOR-swizzled Vt tile). Accumulator is O^T:
// row d=16c+4quad+r, col query=i16 -> vectorized f32x4 epilogue store.
__global__ __launch_bounds__(512, 2)
void gqa_fwd(const float* __restrict__ qg, const __bf16* __restrict__ khi_g,
             const __bf16* __restrict__ klo_g, const __bf16* __restrict__ vt_g,
             float* __restrict__ outg)
{
  // swizzled layouts: K*[s][chunk'=chunk^(s&15)] (16-chunk rows, 256B)
  //                   Vs[d][chunk'=chunk^(d&7)]  (8-chunk rows, 128B)
  __shared__ alignas(16) __bf16 Kh[2][BN * D];   // 2 x 16KB
  __shared__ alignas(16) __bf16 Kl[2][BN * D];   // 2 x 16KB
  __shared__ alignas(16) __bf16 Vs[2][D * BN];   // 2 x 16KB  (total 96KB)

  // XCD swizzle: 512 blocks, 64 per XCD, each XCD owns 2 KV heads (~3MB L2 set).
  const int bid   = blockIdx.x;
  const int xcd   = bid & 7;
  const int idx   = bid >> 3;           // 0..63
  const int bh    = 2 * xcd + (idx & 1);
  const int grp   = (idx >> 1) & 3;
  const int qtile = idx >> 3;           // 0..7
  const int bhg   = bh * 4 + grp;

  const int tid  = threadIdx.x;
  const int wave = tid >> 6;            // 0..7
  const int lane = tid & 63;
  const int i16  = lane & 15;
  const int quad = lane >> 4;

  const float*  qbase = qg + (size_t)bhg * (LQ * D) + (size_t)(qtile * BM) * D;
  const __bf16* khb   = khi_g + (size_t)bh * (SK * D);
  const __bf16* klb   = klo_g + (size_t)bh * (SK * D);
  const __bf16* vtb   = vt_g + (size_t)bh * (D * SK);   // [d][s]

  // per-wave staging: 6 x global_load_lds(16B), src-swizzled, linear LDS dest
  auto stage = [&](int s0, int buf) {
#pragma unroll
    for (int c = 0; c < 2; ++c) {
      const int wc   = 2 * wave + c;          // chunk id 0..15 (1KB each)
      const int srow = wc * 4 + (lane >> 4);  // K: 4 rows of 256B per chunk
      const int jk   = (lane & 15) ^ (srow & 15);
      load_lds16(khb + (size_t)(s0 + srow) * D + 8 * jk, (char*)&Kh[buf][0] + wc * 1024);
      load_lds16(klb + (size_t)(s0 + srow) * D + 8 * jk, (char*)&Kl[buf][0] + wc * 1024);
      const int drow = wc * 8 + (lane >> 3);  // V: 8 rows of 128B per chunk
      const int jv   = (lane & 7) ^ (drow & 7);
      load_lds16(vtb + (size_t)drow * SK + s0 + 8 * jv, (char*)&Vs[buf][0] + wc * 1024);
    }
  };

  // prologue: stage tile 0 into buf 0 (overlaps the Q-fragment load below)
  stage(0, 0);

  // ---- Q fragments, persistent hi/lo. Wave w owns rows [32w,32w+32).
  bf16x8 qhi[2][4], qlo[2][4];
#pragma unroll
  for (int u = 0; u < 2; ++u) {
    const float* qp = qbase + (size_t)(32 * wave + 16 * u + i16) * D + 8 * quad;
#pragma unroll
    for (int t = 0; t < 4; ++t) {
      f32x4 a = *(const f32x4*)(qp + 32 * t);
      f32x4 b = *(const f32x4*)(qp + 32 * t + 4);
#pragma unroll
      for (int j = 0; j < 4; ++j) {
        qhi[u][t][j]     = (__bf16)a[j];
        qlo[u][t][j]     = (__bf16)(a[j] - (float)qhi[u][t][j]);
        qhi[u][t][j + 4] = (__bf16)b[j];
        qlo[u][t][j + 4] = (__bf16)(b[j] - (float)qhi[u][t][j + 4]);
      }
    }
  }

  f32x4 o_acc[2][8];
#pragma unroll
  for (int u = 0; u < 2; ++u)
#pragma unroll
    for (int c = 0; c < 8; ++c) o_acc[u][c] = (f32x4){0.f, 0.f, 0.f, 0.f};
  float m_r[2] = {-INFINITY, -INFINITY};
  float l_r[2] = {0.f, 0.f};

  asm volatile("s_waitcnt vmcnt(0)" ::: "memory");
  __syncthreads();

  for (int it = 0; it < SK / BN; ++it) {
    const int cur = it & 1;
    const __bf16* khc = &Kh[cur][0];
    const __bf16* klc = &Kl[cur][0];
    const __bf16* vsc = &Vs[cur][0];

    // issue next tile's staging FIRST; latency hides under ~5k cycles of MFMA
    if (it + 1 < SK / BN) stage((it + 1) * BN, cur ^ 1);

    // ---- S^T = K Q^T (hi/lo bf16 split; fragments from swizzled LDS)
    f32x4 sf[2][4];
#pragma unroll
    for (int u = 0; u < 2; ++u)
#pragma unroll
      for (int n = 0; n < 4; ++n) sf[u][n] = (f32x4){0.f, 0.f, 0.f, 0.f};
#pragma unroll
    for (int n = 0; n < 4; ++n) {
#pragma unroll
      for (int t = 0; t < 4; ++t) {
        const int ke = (16 * n + i16) * 128 + 8 * ((4 * t + quad) ^ i16);
        bf16x8 kh = *(const bf16x8*)&khc[ke];
        bf16x8 kl = *(const bf16x8*)&klc[ke];
#pragma unroll
        for (int u = 0; u < 2; ++u) {
          sf[u][n] = __builtin_amdgcn_mfma_f32_16x16x32_bf16(kh, qhi[u][t], sf[u][n], 0, 0, 0);
          sf[u][n] = __builtin_amdgcn_mfma_f32_16x16x32_bf16(kh, qlo[u][t], sf[u][n], 0, 0, 0);
          sf[u][n] = __builtin_amdgcn_mfma_f32_16x16x32_bf16(kl, qhi[u][t], sf[u][n], 0, 0, 0);
        }
      }
    }
    // sf[u][n][r] = S[key=16n+4quad+r][query=32w+16u+i16]

    // ---- lane-local online softmax + in-register P^T fragments
    bf16x8 pb[2][2];
#pragma unroll
    for (int u = 0; u < 2; ++u) {
      float mx = sf[u][0][0];
#pragma unroll
      for (int n = 0; n < 4; ++n)
#pragma unroll
        for (int r = 0; r < 4; ++r) mx = fmaxf(mx, sf[u][n][r]);
      mx = fmaxf(mx, __shfl_xor(mx, 16, 64));
      mx = fmaxf(mx, __shfl_xor(mx, 32, 64));
      const float mnew  = fmaxf(m_r[u], mx);
      const float alpha = __expf(m_r[u] - mnew);   // first iter: exp(-inf)=0
      m_r[u] = mnew;
      float rs = 0.f;
      // k-slot j of PV tile t holds key kappa=32t+16(j>>2)+4quad+(j&3)
      //  -> pb[u][t][4h+r] = P for key 16(2t+h)+4quad+r : all lane-local.
#pragma unroll
      for (int t = 0; t < 2; ++t) {
#pragma unroll
        for (int h = 0; h < 2; ++h) {
#pragma unroll
          for (int r = 0; r < 4; ++r) {
            const float p  = __expf(sf[u][2 * t + h][r] - mnew);
            const __bf16 pbv = (__bf16)p;
            pb[u][t][4 * h + r] = pbv;
            rs += (float)pbv;   // l consistent with bf16 P fed to P*V
          }
        }
      }
      rs += __shfl_xor(rs, 16, 64);
      rs += __shfl_xor(rs, 32, 64);
      l_r[u] = l_r[u] * alpha + rs;
#pragma unroll
      for (int c = 0; c < 8; ++c)
#pragma unroll
        for (int r = 0; r < 4; ++r) o_acc[u][c][r] *= alpha;
    }

    // ---- O^T += V^T P^T (V-frag follows the same kappa key permutation)
#pragma unroll
    for (int c = 0; c < 8; ++c) {
      const int vbase = (16 * c + i16) * 64 + 4 * (quad & 1);
      const int xh    = i16 & 7;
#pragma unroll
      for (int t = 0; t < 2; ++t) {
        const int c0 = (4 * t + (quad >> 1)) ^ xh;
        const int c1 = (4 * t + 2 + (quad >> 1)) ^ xh;
        bf16x4 v0 = *(const bf16x4*)&vsc[vbase + 8 * c0];
        bf16x4 v1 = *(const bf16x4*)&vsc[vbase + 8 * c1];
        bf16x8 av = __builtin_shufflevector(v0, v1, 0, 1, 2, 3, 4, 5, 6, 7);
#pragma unroll
        for (int u = 0; u < 2; ++u)
          o_acc[u][c] = __builtin_amdgcn_mfma_f32_16x16x32_bf16(av, pb[u][t], o_acc[u][c], 0, 0, 0);
      }
    }

    // staging for tile it+1 has had a full compute phase to land
    asm volatile("s_waitcnt vmcnt(0)" ::: "memory");
    __syncthreads();
  }

  // ---- epilogue: O^T accumulator -> contiguous f32x4 stores
  float* obase = outg + (size_t)bhg * (LQ * D) + (size_t)(qtile * BM) * D;
#pragma unroll
  for (int u = 0; u < 2; ++u) {
    const float inv = 1.f / l_r[u];
    float* op = obase + (size_t)(32 * wave + 16 * u + i16) * D;
#pragma unroll
    for (int c = 0; c < 8; ++c) {
      f32x4 r4 = o_acc[u][c] * inv;      // r component = d offset 4*quad+r
      *(f32x4*)(op + 16 * c + 4 * quad) = r4;
    }
  }
}

extern "C" void kernel_launch(void* const* d_in, const int* in_sizes, int n_in,
                              void* d_out, int out_size, void* d_ws, size_t ws_size,
                              hipStream_t stream) {
  const float* q = (const float*)d_in[0];
  const float* k = (const float*)d_in[1];
  const float* v = (const float*)d_in[2];
  float* out = (float*)d_out;
  (void)in_sizes; (void)n_in; (void)out_size; (void)ws_size;

  const size_t kv_elems = (size_t)NKV * SK * D;          // 4.19M
  __bf16* khi = (__bf16*)d_ws;                           // 8.39 MB
  __bf16* klo = khi + kv_elems;                          // 8.39 MB
  __bf16* vt  = klo + kv_elems;                          // 8.39 MB

  conv_k<<<dim3(kv_elems / (256 * 4)), 256, 0, stream>>>(k, khi, klo);
  transpose_v<<<dim3(NKV * 64), 256, 0, stream>>>(v, vt);
  gqa_fwd<<<dim3(8 * (LQ / BM) * 8), 512, 0, stream>>>(q, khi, klo, vt, out);
}